// Round 9
// baseline (76.625 us; speedup 1.0000x reference)
//
#include <hip/hip_runtime.h>

typedef _Float16 f16;
typedef _Float16 f16x4 __attribute__((ext_vector_type(4)));
typedef _Float16 f16x8 __attribute__((ext_vector_type(8)));
typedef float    f32x4 __attribute__((ext_vector_type(4)));

#define NB 32
#define ND 256
#define NT 1024
#define MAGIC64 0x5A5A3C3CA5A5C3C3ull

// ---------------------------------------------------------------------------
// ONE dispatch: 256 blocks x 512 threads, launch_bounds(512,2) -> VGPR cap
// 256 (no spill), LDS 34 KB -> 1 block/CU guaranteed => all 256 co-resident,
// flag spin deadlock-free.
//
// Phase 0 (blocks 0..15): W fragment prep -> wf, release wflags[g].
//   wf[ks8(8)][nt(16)][lane(64)][j(8)] = Wm[nt*16+(lane&15)][ks8*32+(lane>>4)*8+j]
// Phase 1 (all blocks): lean checkpoint IIR scan of rows [32g,32g+32)
//   (wave w: rows 32g+4w+{0..3}, next row prefetched). Only running states:
//   local 16-fold -> weighted Kogge-Stone -> odd lane 2c-1 = state entering
//   t=32c. chk[row][c]. Release cflags[g].
// Phase 2 (block g -> b=g>>3, tiles tt=(g&7)*2+{0,1}): spin on 16 wflags +
//   8 cohort cflags (cohort CLOSED: batch b's consumers == its producers).
//   Per tile (R8-proven body): recompute y (32 steps from chk, x is L2/L3-
//   warm) straight into Yl (transposed [t][m], XOR swizzle idx^=(t&7)<<3),
//   MFMA vs A-frags from wf (L2), epilogue sum_n y*(z+1), out = part - 70.
//
// Replay-idempotence: chk/wf bytes identical every replay; stale MAGIC flags
// short-cut the spin harmlessly (R5/R7-validated protocol).
// ---------------------------------------------------------------------------
__global__ __launch_bounds__(512, 2) void dbnn_one_kernel(
    const float* __restrict__ x, const float* __restrict__ tau_rise,
    const float* __restrict__ tau_decay, const float* __restrict__ omega,
    const float* __restrict__ W, float2* __restrict__ chk,
    f16* __restrict__ wf, unsigned long long* __restrict__ cflags,
    unsigned long long* __restrict__ wflags, float* __restrict__ out)
{
    __shared__ __align__(16) f16 Yl[16384];    // 32 KB (64 t x 256 m)
    __shared__ float sbuf[8][64];              // 2 KB cross-wave partials

    const int tid  = threadIdx.x;
    const int lane = tid & 63;
    const int w    = tid >> 6;
    const int g    = blockIdx.x;

    // ---------------- phase 0: W fragment prep (blocks 0..15) -------------
    if (g < 16) {
        const int gid  = g * 512 + tid;        // 0..8191
        const int ks8  = gid >> 10;
        const int nt   = (gid >> 6) & 15;
        const int ln   = gid & 63;
        const int nrow = nt * 16 + (ln & 15);
        const int k0   = ks8 * 32 + (ln >> 4) * 8;
        f16x8 v;
        #pragma unroll
        for (int j = 0; j < 8; ++j) {
            int k = k0 + j;
            float wv = W[nrow * 256 + k];
            v[j] = (f16)((k == nrow) ? 0.0f : wv);
        }
        *reinterpret_cast<f16x8*>(wf + (size_t)gid * 8) = v;
        __syncthreads();
        if (tid == 0) {
            __threadfence();
            __hip_atomic_store(&wflags[g], MAGIC64,
                               __ATOMIC_RELEASE, __HIP_MEMORY_SCOPE_AGENT);
        }
    }

    // ---------------- phase 1: checkpoint scan, 4 rows per wave -----------
    {
        const int row0 = g * 32 + w * 4;
        const float* xp = x + (size_t)row0 * NT + lane * 16;

        f32x4 cur[4], nxt[4];
        #pragma unroll
        for (int i = 0; i < 4; ++i)
            cur[i] = *reinterpret_cast<const f32x4*>(xp + i * 4);

        #pragma unroll
        for (int j = 0; j < 4; ++j) {
            if (j < 3) {
                #pragma unroll
                for (int i = 0; i < 4; ++i)
                    nxt[i] = *reinterpret_cast<const f32x4*>(
                        xp + (size_t)(j + 1) * NT + i * 4);
            }
            const int row = row0 + j;
            const int n   = row & (ND - 1);
            const float ad = expf(-1.0f / tau_decay[n]);
            const float am = expf(-(1.0f / tau_rise[n] + 1.0f / tau_decay[n]));

            // local 16-step fold
            float sd = 0.f, sm = 0.f;
            #pragma unroll
            for (int i = 0; i < 4; ++i) {
                #pragma unroll
                for (int e = 0; e < 4; ++e) {
                    sd = fmaf(ad, sd, cur[i][e]);
                    sm = fmaf(am, sm, cur[i][e]);
                }
            }
            // a^16 ladders
            float t2;
            t2 = ad*ad; t2 = t2*t2; t2 = t2*t2; float wd = t2*t2;
            t2 = am*am; t2 = t2*t2; t2 = t2*t2; float wm = t2*t2;

            // weighted Kogge-Stone: X_l = state at end of t=16(l+1)-1
            float Xd = sd, Xm = sm;
            #pragma unroll
            for (int off = 1; off < 64; off <<= 1) {
                float pd = __shfl_up(Xd, off);
                float pm = __shfl_up(Xm, off);
                if (lane >= off) { Xd = fmaf(wd, pd, Xd); Xm = fmaf(wm, pm, Xm); }
                wd *= wd; wm *= wm;
            }
            float2* cr = chk + (size_t)row * 32;
            if (lane == 0) cr[0] = make_float2(0.f, 0.f);
            if ((lane & 1) && lane < 63) cr[(lane + 1) >> 1] = make_float2(Xd, Xm);

            #pragma unroll
            for (int i = 0; i < 4; ++i) cur[i] = nxt[i];
        }
    }

    // ---------------- release own chk flag --------------------------------
    __syncthreads();
    if (tid == 0) {
        __threadfence();
        __hip_atomic_store(&cflags[g], MAGIC64,
                           __ATOMIC_RELEASE, __HIP_MEMORY_SCOPE_AGENT);
    }

    // ---------------- acquire: 16 wflags + 8 cohort cflags ----------------
    const int b = g >> 3;
    if (tid == 0) {
        #pragma unroll 1
        for (int p = 0; p < 16; ++p)
            while (__hip_atomic_load(&wflags[p], __ATOMIC_ACQUIRE,
                                     __HIP_MEMORY_SCOPE_AGENT) != MAGIC64)
                __builtin_amdgcn_s_sleep(2);
        const int base = b << 3;
        #pragma unroll 1
        for (int p = 0; p < 8; ++p)
            while (__hip_atomic_load(&cflags[base + p], __ATOMIC_ACQUIRE,
                                     __HIP_MEMORY_SCOPE_AGENT) != MAGIC64)
                __builtin_amdgcn_s_sleep(2);
    }
    __syncthreads();

    // ---------------- phase 2: two bilinear t-tiles (R8-proven body) ------
    const int gq = lane >> 4;
    int tl4[4], sw4[4];
    #pragma unroll
    for (int tf = 0; tf < 4; ++tf) {
        tl4[tf] = tf * 16 + (lane & 15);
        sw4[tf] = (tl4[tf] & 7) << 3;
    }

    #pragma unroll 1
    for (int sub = 0; sub < 2; ++sub) {
        const int tt = (g & 7) * 2 + sub;
        const int t0 = tt * 64;

        // recompute y tile from x (L2/L3-warm) + checkpoint
        {
            const int m = tid >> 1;            // row n within batch
            const int h = tid & 1;             // t-half of 32
            const int rowg = b * ND + m;
            const float ad = expf(-1.0f / tau_decay[m]);
            const float am = expf(-(1.0f / tau_rise[m] + 1.0f / tau_decay[m]));
            const float om = omega[m];

            const float* xs = x + (size_t)rowg * NT + t0 + h * 32;
            f32x4 xv[8];
            #pragma unroll
            for (int c = 0; c < 8; ++c)
                xv[c] = *reinterpret_cast<const f32x4*>(xs + c * 4);

            float2 ck = chk[(size_t)rowg * 32 + tt * 2 + h];
            float Sd = ck.x, Sm = ck.y;
            #pragma unroll
            for (int i = 0; i < 32; ++i) {
                float xi = xv[i >> 2][i & 3];
                Sd = fmaf(ad, Sd, xi);
                Sm = fmaf(am, Sm, xi);
                float yv = om * (Sd - Sm);
                int tl = h * 32 + i;
                Yl[tl * 256 + (m ^ ((tl & 7) << 3))] = (f16)yv;
            }
        }
        __syncthreads();

        f32x4 acc[2][4];                    // [a: n-frag][tf]
        #pragma unroll
        for (int a = 0; a < 2; ++a)
            #pragma unroll
            for (int tf = 0; tf < 4; ++tf) acc[a][tf] = (f32x4){0.f,0.f,0.f,0.f};

        #pragma unroll
        for (int ks = 0; ks < 8; ++ks) {
            f16x8 afrag[2];
            #pragma unroll
            for (int a = 0; a < 2; ++a)
                afrag[a] = *reinterpret_cast<const f16x8*>(
                    &wf[(size_t)(((ks * 16) + (2 * w + a)) * 64 + lane) * 8]);
            f16x8 bfrag[4];
            #pragma unroll
            for (int tf = 0; tf < 4; ++tf) {
                int m0 = ks * 32 + gq * 8;
                bfrag[tf] = *reinterpret_cast<const f16x8*>(
                    &Yl[tl4[tf] * 256 + (m0 ^ sw4[tf])]);
            }
            #pragma unroll
            for (int a = 0; a < 2; ++a)
                #pragma unroll
                for (int tf = 0; tf < 4; ++tf)
                    acc[a][tf] = __builtin_amdgcn_mfma_f32_16x16x32_f16(
                        afrag[a], bfrag[tf], acc[a][tf], 0, 0, 0);
        }

        // epilogue: per t-col partial over this wave's 32 n of y*(z+1)
        #pragma unroll
        for (int tf = 0; tf < 4; ++tf) {
            float p = 0.f;
            #pragma unroll
            for (int a = 0; a < 2; ++a) {
                int n0 = w * 32 + a * 16 + gq * 4;
                f16x4 yv4 = *reinterpret_cast<const f16x4*>(
                    &Yl[tl4[tf] * 256 + (n0 ^ sw4[tf])]);
                #pragma unroll
                for (int r = 0; r < 4; ++r)
                    p = fmaf((float)yv4[r], acc[a][tf][r] + 1.0f, p);
            }
            p += __shfl_xor(p, 16);
            p += __shfl_xor(p, 32);
            if (lane < 16) sbuf[w][tf * 16 + lane] = p;
        }
        __syncthreads();
        if (tid < 64) {
            float s = sbuf[0][tid] + sbuf[1][tid] + sbuf[2][tid] + sbuf[3][tid]
                    + sbuf[4][tid] + sbuf[5][tid] + sbuf[6][tid] + sbuf[7][tid];
            out[b * NT + t0 + tid] = s - 70.0f;
        }
        __syncthreads();   // Yl/sbuf safe to overwrite next sub-tile
    }
}

// ---------------------------------------------------------------------------
extern "C" void kernel_launch(void* const* d_in, const int* in_sizes, int n_in,
                              void* d_out, int out_size, void* d_ws, size_t ws_size,
                              hipStream_t stream) {
    const float* x         = (const float*)d_in[0];
    const float* tau_rise  = (const float*)d_in[1];
    const float* tau_decay = (const float*)d_in[2];
    const float* omega     = (const float*)d_in[3];
    const float* W         = (const float*)d_in[4];
    float* out = (float*)d_out;

    float2* chk = (float2*)d_ws;                                    // 2 MB
    f16*    wfr = (f16*)((char*)d_ws + (size_t)4 * 1024 * 1024);    // 128 KB
    unsigned long long* cflags =
        (unsigned long long*)((char*)d_ws + (size_t)8 * 1024 * 1024);  // 2 KB
    unsigned long long* wflags =
        (unsigned long long*)((char*)d_ws + (size_t)8 * 1024 * 1024 + 4096);

    dbnn_one_kernel<<<256, 512, 0, stream>>>(
        x, tau_rise, tau_decay, omega, W, chk, wfr, cflags, wflags, out);
}

// Round 11
// 24.989 us; speedup vs baseline: 3.0663x; 3.0663x over previous
//
#include <hip/hip_runtime.h>

typedef _Float16 f16;
typedef _Float16 f16x4 __attribute__((ext_vector_type(4)));
typedef _Float16 f16x8 __attribute__((ext_vector_type(8)));
typedef float    f32x4 __attribute__((ext_vector_type(4)));

#define NB 32
#define ND 256
#define NT 1024

// ---------------------------------------------------------------------------
// Kernel 1 (R3/R6-proven, verbatim): blocks [0,2048) = depthwise causal conv
// via IIR scan; blocks >=2048 = W fragment prep.
//
// IIR: one wave per (b,n) row; lane l owns t in [16l,16l+16).
// k[u] = om*(d^u - m^u) => y = om*(S_d - S_m), S_a[t] = x[t] + a*S_a[t-1].
//
// W prep layout: wf[ks8(8)][nt(16)][lane(64)][j(8)],
//   value = Wm[n = nt*16+(lane&15)][k = ks8*32+(lane>>4)*8+j], diag=0.
// ---------------------------------------------------------------------------
__global__ __launch_bounds__(256) void iir_wprep_kernel(
    const float* __restrict__ x, const float* __restrict__ tau_rise,
    const float* __restrict__ tau_decay, const float* __restrict__ omega,
    const float* __restrict__ W, f16* __restrict__ y16, f16* __restrict__ wf)
{
    if (blockIdx.x >= 2048) {
        const int gid  = (blockIdx.x - 2048) * 256 + threadIdx.x;  // 0..8191
        const int ks8  = gid >> 10;
        const int nt   = (gid >> 6) & 15;
        const int lane = gid & 63;
        const int nrow = nt * 16 + (lane & 15);
        const int k0   = ks8 * 32 + (lane >> 4) * 8;
        f16x8 v;
        #pragma unroll
        for (int j = 0; j < 8; ++j) {
            int k = k0 + j;
            float w = W[nrow * 256 + k];
            v[j] = (f16)((k == nrow) ? 0.0f : w);
        }
        *reinterpret_cast<f16x8*>(wf + (size_t)gid * 8) = v;
        return;
    }

    const int lane = threadIdx.x & 63;
    const int wid  = threadIdx.x >> 6;
    const int row  = blockIdx.x * 4 + wid;      // b*ND + n
    const int n    = row & (ND - 1);

    const float td = tau_decay[n];
    const float tr = tau_rise[n];
    const float om = omega[n];
    const float ad = expf(-1.0f / td);
    const float am = expf(-(1.0f / tr + 1.0f / td));

    const float* xr = x + (size_t)row * NT + lane * 16;
    float xv[16];
    #pragma unroll
    for (int i = 0; i < 4; ++i) {
        f32x4 v = *reinterpret_cast<const f32x4*>(xr + i * 4);
        xv[i*4+0] = v[0]; xv[i*4+1] = v[1]; xv[i*4+2] = v[2]; xv[i*4+3] = v[3];
    }

    // local (carry-free) inclusive scans, both states
    float ld[16], lm[16];
    float sd = 0.f, sm = 0.f;
    #pragma unroll
    for (int i = 0; i < 16; ++i) {
        sd = fmaf(ad, sd, xv[i]); ld[i] = sd;
        sm = fmaf(am, sm, xv[i]); lm[i] = sm;
    }

    // a^16 for each state
    float t2;
    t2 = ad * ad; t2 = t2 * t2; t2 = t2 * t2; const float a16d = t2 * t2;
    t2 = am * am; t2 = t2 * t2; t2 = t2 * t2; const float a16m = t2 * t2;

    // weighted Kogge-Stone across lanes: X_l = sum_j a16^(l-j) H_j
    float Xd = sd, Xm = sm;
    float wdp = a16d, wmp = a16m;
    #pragma unroll
    for (int off = 1; off < 64; off <<= 1) {
        float pd = __shfl_up(Xd, off);
        float pm = __shfl_up(Xm, off);
        if (lane >= off) { Xd = fmaf(wdp, pd, Xd); Xm = fmaf(wmp, pm, Xm); }
        wdp *= wdp; wmp *= wmp;
    }
    // exclusive carry = running state at end of previous lane's chunk
    float cd = __shfl_up(Xd, 1);
    float cm = __shfl_up(Xm, 1);
    if (lane == 0) { cd = 0.f; cm = 0.f; }

    // reconstruct: S[16l+i] = local_i + a^(i+1) * carry
    f16x8 o0, o1;
    float pd = ad, pm = am;
    #pragma unroll
    for (int i = 0; i < 16; ++i) {
        float yd = fmaf(pd, cd, ld[i]);
        float ym = fmaf(pm, cm, lm[i]);
        float yv = om * (yd - ym);
        if (i < 8) o0[i] = (f16)yv; else o1[i - 8] = (f16)yv;
        pd *= ad; pm *= am;
    }
    f16* dst = y16 + (size_t)row * NT + lane * 16;
    *reinterpret_cast<f16x8*>(dst)     = o0;
    *reinterpret_cast<f16x8*>(dst + 8) = o1;
}

// ---------------------------------------------------------------------------
// Kernel 2: out[b,t] = sum_n y[n,t]*(z[n,t]+1) - 70,  z = Wm*y  (per b).
// Block = (b, t-tile of 64), 256 threads = 4 waves; wave w owns n-range
// [64w, 64w+64), all 64 t -> per ks: 4 A-frags + 4 B-frags -> 16 MFMAs
// (halves LDS-read insts vs 32n-wave tiling). A-frags from global wf
// (L2-resident) with named aA/aB double-buffer (no hoist explosion).
// Stage: thread owns 4 consecutive m rows x 16 t -> packed ds_write_b64
// (4x fewer LDS write insts than scalar). Yl transposed [t][m], XOR swizzle
// (u16 idx ^= (t&7)<<3). Cross-wave n-reduction via sbuf.
// ---------------------------------------------------------------------------
__global__ __launch_bounds__(256, 2) void bilinear_kernel(
    const f16* __restrict__ y16, const f16* __restrict__ wf,
    float* __restrict__ out)
{
    __shared__ __align__(16) f16 Yl[16384];    // 32 KB (64 t x 256 m)
    __shared__ float sbuf[4][64];              // 1 KB cross-wave partials

    const int bi = blockIdx.x;
    const int tt = bi & 15;
    const int b  = bi >> 4;
    const int t0 = tt * 64;
    const int tid = threadIdx.x;

    // ---- stage Y tile: thread (j2 = tid&63 -> m = 4*j2+r, h = tid>>6 ->
    //      t in [16h,16h+16)); packed f16x4 writes along m ----
    {
        const int j2 = tid & 63;
        const int h  = tid >> 6;
        const f16* base = y16 + ((size_t)(b * ND + 4 * j2)) * NT + t0 + h * 16;
        f16x8 vy[4][2];
        #pragma unroll
        for (int r = 0; r < 4; ++r) {
            vy[r][0] = *reinterpret_cast<const f16x8*>(base + (size_t)r * NT);
            vy[r][1] = *reinterpret_cast<const f16x8*>(base + (size_t)r * NT + 8);
        }
        #pragma unroll
        for (int i = 0; i < 16; ++i) {
            const int tl = h * 16 + i;
            f16x4 v4;
            v4[0] = vy[0][i >> 3][i & 7];
            v4[1] = vy[1][i >> 3][i & 7];
            v4[2] = vy[2][i >> 3][i & 7];
            v4[3] = vy[3][i >> 3][i & 7];
            *reinterpret_cast<f16x4*>(
                &Yl[tl * 256 + ((4 * j2) ^ ((tl & 7) << 3))]) = v4;
        }
    }
    __syncthreads();

    const int lane = tid & 63;
    const int w    = tid >> 6;          // wave: n-range [64w, 64w+64)
    const int gq   = lane >> 4;

    int tl4[4], sw4[4];
    #pragma unroll
    for (int tf = 0; tf < 4; ++tf) {
        tl4[tf] = tf * 16 + (lane & 15);
        sw4[tf] = (tl4[tf] & 7) << 3;
    }

    f32x4 acc[4][4];                    // [a: n-frag][tf]
    #pragma unroll
    for (int a = 0; a < 4; ++a)
        #pragma unroll
        for (int tf = 0; tf < 4; ++tf) acc[a][tf] = (f32x4){0.f,0.f,0.f,0.f};

    // A-frag base for this wave: nt = 4w + a at K-slice ks; stride between
    // consecutive nt (or ks*16) slots is 64 lanes * 8 f16 = 512 f16.
    const f16* wbase = wf + (size_t)(4 * w) * 512 + (size_t)lane * 8;

    f16x8 aA[4], aB[4];
    #pragma unroll
    for (int a_ = 0; a_ < 4; ++a_)
        aA[a_] = *reinterpret_cast<const f16x8*>(wbase + (size_t)a_ * 512);

    #pragma unroll
    for (int kp = 0; kp < 4; ++kp) {
        const int ks0 = 2 * kp, ks1 = 2 * kp + 1;
        // prefetch odd slice
        #pragma unroll
        for (int a_ = 0; a_ < 4; ++a_)
            aB[a_] = *reinterpret_cast<const f16x8*>(
                wbase + (size_t)(ks1 * 16 + a_) * 512);
        // compute even slice
        {
            f16x8 bfrag[4];
            #pragma unroll
            for (int tf = 0; tf < 4; ++tf) {
                int m0 = ks0 * 32 + gq * 8;
                bfrag[tf] = *reinterpret_cast<const f16x8*>(
                    &Yl[tl4[tf] * 256 + (m0 ^ sw4[tf])]);
            }
            #pragma unroll
            for (int a = 0; a < 4; ++a)
                #pragma unroll
                for (int tf = 0; tf < 4; ++tf)
                    acc[a][tf] = __builtin_amdgcn_mfma_f32_16x16x32_f16(
                        aA[a], bfrag[tf], acc[a][tf], 0, 0, 0);
        }
        // prefetch next even slice
        if (kp < 3) {
            #pragma unroll
            for (int a_ = 0; a_ < 4; ++a_)
                aA[a_] = *reinterpret_cast<const f16x8*>(
                    wbase + (size_t)((ks1 + 1) * 16 + a_) * 512);
        }
        // compute odd slice
        {
            f16x8 bfrag[4];
            #pragma unroll
            for (int tf = 0; tf < 4; ++tf) {
                int m0 = ks1 * 32 + gq * 8;
                bfrag[tf] = *reinterpret_cast<const f16x8*>(
                    &Yl[tl4[tf] * 256 + (m0 ^ sw4[tf])]);
            }
            #pragma unroll
            for (int a = 0; a < 4; ++a)
                #pragma unroll
                for (int tf = 0; tf < 4; ++tf)
                    acc[a][tf] = __builtin_amdgcn_mfma_f32_16x16x32_f16(
                        aB[a], bfrag[tf], acc[a][tf], 0, 0, 0);
        }
    }

    // epilogue: per t-col partial = sum over this wave's 64 n of y*(z+1)
    #pragma unroll
    for (int tf = 0; tf < 4; ++tf) {
        float p = 0.f;
        #pragma unroll
        for (int a = 0; a < 4; ++a) {
            int n0 = 64 * w + 16 * a + 4 * gq;
            f16x4 yv4 = *reinterpret_cast<const f16x4*>(
                &Yl[tl4[tf] * 256 + (n0 ^ sw4[tf])]);
            #pragma unroll
            for (int r = 0; r < 4; ++r)
                p = fmaf((float)yv4[r], acc[a][tf][r] + 1.0f, p);
        }
        p += __shfl_xor(p, 16);
        p += __shfl_xor(p, 32);
        if (lane < 16) sbuf[w][tf * 16 + lane] = p;
    }
    __syncthreads();
    if (tid < 64) {
        float s = sbuf[0][tid] + sbuf[1][tid] + sbuf[2][tid] + sbuf[3][tid];
        out[b * NT + t0 + tid] = s - 70.0f;
    }
}

// ---------------------------------------------------------------------------
extern "C" void kernel_launch(void* const* d_in, const int* in_sizes, int n_in,
                              void* d_out, int out_size, void* d_ws, size_t ws_size,
                              hipStream_t stream) {
    const float* x         = (const float*)d_in[0];
    const float* tau_rise  = (const float*)d_in[1];
    const float* tau_decay = (const float*)d_in[2];
    const float* omega     = (const float*)d_in[3];
    const float* W         = (const float*)d_in[4];
    float* out = (float*)d_out;

    f16* y16 = (f16*)d_ws;                                        // 16 MB
    f16* wfr = (f16*)((char*)d_ws + (size_t)16 * 1024 * 1024);    // 128 KB

    iir_wprep_kernel<<<2048 + 32, 256, 0, stream>>>(
        x, tau_rise, tau_decay, omega, W, y16, wfr);
    bilinear_kernel<<<NB * 16, 256, 0, stream>>>(y16, wfr, out);
}